// Round 1
// baseline (382.311 us; speedup 1.0000x reference)
//
#include <hip/hip_runtime.h>
#include <math.h>

// Problem constants: x[B][L][C] f32, top-3 min (ascending) + top-3 max (descending) over L.
#define NB 32
#define NL 8192
#define NC 256

// Branchless sorted-insert into (m1<=m2<=m3) three-smallest and (M1>=M2>=M3) three-largest.
// m2' = med3(m1,m2,v); m3' = min(m3, max(m2,v)); m1' = min(m1,v).  (symmetric for max side)
__device__ __forceinline__ void upd6(float v,
                                     float& m1, float& m2, float& m3,
                                     float& M1, float& M2, float& M3) {
    float nm3 = fminf(m3, fmaxf(m2, v));
    float nm2 = __builtin_amdgcn_fmed3f(m1, m2, v);
    m1 = fminf(m1, v);
    m2 = nm2;
    m3 = nm3;
    float nM3 = fmaxf(M3, fminf(M2, v));
    float nM2 = __builtin_amdgcn_fmed3f(M1, M2, v);
    M1 = fmaxf(M1, v);
    M2 = nM2;
    M3 = nM3;
}

// Pass 1: grid = NB*S blocks, 256 threads. Thread t: c4 = (t&63)*4 channels, sub = t>>6.
// Each thread scans NL/(4S) consecutive l-rows with float4 loads (wave reads full 1KB C-row).
// Partials written to ws[b][p][k][c] (k = m1,m2,m3,M1,M2,M3) as coalesced float4 stores.
__global__ __launch_bounds__(256) void pass1_partials(const float* __restrict__ x,
                                                      float* __restrict__ ws, int S) {
    const int b   = blockIdx.x / S;
    const int s   = blockIdx.x - b * S;
    const int t   = threadIdx.x;
    const int c4  = (t & 63) << 2;
    const int sub = t >> 6;
    const int P   = S << 2;
    const int p   = (s << 2) + sub;
    const int chunk = NL / P;           // l-rows per thread
    const int l0    = p * chunk;

    const float* base = x + ((size_t)b * NL + l0) * NC + c4;

    float m1[4], m2[4], m3[4], M1[4], M2[4], M3[4];
#pragma unroll
    for (int j = 0; j < 4; ++j) {
        m1[j] = m2[j] = m3[j] = INFINITY;
        M1[j] = M2[j] = M3[j] = -INFINITY;
    }

#pragma unroll 4
    for (int i = 0; i < chunk; ++i) {
        float4 v = *(const float4*)(base + (size_t)i * NC);
        upd6(v.x, m1[0], m2[0], m3[0], M1[0], M2[0], M3[0]);
        upd6(v.y, m1[1], m2[1], m3[1], M1[1], M2[1], M3[1]);
        upd6(v.z, m1[2], m2[2], m3[2], M1[2], M2[2], M3[2]);
        upd6(v.w, m1[3], m2[3], m3[3], M1[3], M2[3], M3[3]);
    }

    float* w = ws + ((size_t)(b * P + p) * 6) * NC + c4;
    *(float4*)(w + 0 * NC) = make_float4(m1[0], m1[1], m1[2], m1[3]);
    *(float4*)(w + 1 * NC) = make_float4(m2[0], m2[1], m2[2], m2[3]);
    *(float4*)(w + 2 * NC) = make_float4(m3[0], m3[1], m3[2], m3[3]);
    *(float4*)(w + 3 * NC) = make_float4(M1[0], M1[1], M1[2], M1[3]);
    *(float4*)(w + 4 * NC) = make_float4(M2[0], M2[1], M2[2], M2[3]);
    *(float4*)(w + 5 * NC) = make_float4(M3[0], M3[1], M3[2], M3[3]);
}

// Pass 2: one thread per (b,c). Every partial value is a genuine data element, so all six
// feed the same tracker. Reads coalesced across c; writes 24B contiguous per thread.
__global__ __launch_bounds__(256) void pass2_merge(const float* __restrict__ ws,
                                                   float* __restrict__ out, int P) {
    const int idx = blockIdx.x * 256 + threadIdx.x;   // b*NC + c
    const int b = idx >> 8;
    const int c = idx & 255;

    float m1 = INFINITY, m2 = INFINITY, m3 = INFINITY;
    float M1 = -INFINITY, M2 = -INFINITY, M3 = -INFINITY;

    const float* w = ws + (size_t)b * P * 6 * NC + c;
    for (int p = 0; p < P; ++p) {
        const float* wp = w + (size_t)p * 6 * NC;
#pragma unroll
        for (int k = 0; k < 6; ++k) {
            upd6(wp[(size_t)k * NC], m1, m2, m3, M1, M2, M3);
        }
    }

    float* o = out + (size_t)idx * 6;
    o[0] = m1; o[1] = m2; o[2] = m3;
    o[3] = M1; o[4] = M2; o[5] = M3;
}

// Fallback if workspace is too small: one thread per (b, 4 channels), full-column scan.
__global__ __launch_bounds__(64) void direct_scan(const float* __restrict__ x,
                                                  float* __restrict__ out) {
    const int b  = blockIdx.x;
    const int c4 = threadIdx.x << 2;

    float m1[4], m2[4], m3[4], M1[4], M2[4], M3[4];
#pragma unroll
    for (int j = 0; j < 4; ++j) {
        m1[j] = m2[j] = m3[j] = INFINITY;
        M1[j] = M2[j] = M3[j] = -INFINITY;
    }

    const float* base = x + (size_t)b * NL * NC + c4;
#pragma unroll 4
    for (int i = 0; i < NL; ++i) {
        float4 v = *(const float4*)(base + (size_t)i * NC);
        upd6(v.x, m1[0], m2[0], m3[0], M1[0], M2[0], M3[0]);
        upd6(v.y, m1[1], m2[1], m3[1], M1[1], M2[1], M3[1]);
        upd6(v.z, m1[2], m2[2], m3[2], M1[2], M2[2], M3[2]);
        upd6(v.w, m1[3], m2[3], m3[3], M1[3], M2[3], M3[3]);
    }

#pragma unroll
    for (int j = 0; j < 4; ++j) {
        float* o = out + ((size_t)b * NC + c4 + j) * 6;
        o[0] = m1[j]; o[1] = m2[j]; o[2] = m3[j];
        o[3] = M1[j]; o[4] = M2[j]; o[5] = M3[j];
    }
}

extern "C" void kernel_launch(void* const* d_in, const int* in_sizes, int n_in,
                              void* d_out, int out_size, void* d_ws, size_t ws_size,
                              hipStream_t stream) {
    const float* x = (const float*)d_in[0];
    float* out = (float*)d_out;

    // ws bytes needed for split factor S: NB * (4S) * 6 * NC * 4 = 786432 * S
    int S = 16;
    while (S > 1 && (size_t)786432ULL * (size_t)S > ws_size) S >>= 1;

    if ((size_t)786432ULL * (size_t)S <= ws_size) {
        float* ws = (float*)d_ws;
        pass1_partials<<<NB * S, 256, 0, stream>>>(x, ws, S);
        pass2_merge<<<(NB * NC) / 256, 256, 0, stream>>>(ws, out, S * 4);
    } else {
        direct_scan<<<NB, 64, 0, stream>>>(x, out);
    }
}

// Round 2
// 367.157 us; speedup vs baseline: 1.0413x; 1.0413x over previous
//
#include <hip/hip_runtime.h>
#include <math.h>

// Problem: x[B=32][L=8192][C=256] f32 -> per (b,c): 3 smallest (asc) + 3 largest (desc) over L.
#define NB 32
#define NL 8192
#define NC 256
#define S1 32          // pass-1 split blocks per batch
#define NP (S1 * 4)    // partials per (b,c) = 128
#define CHUNK (NL / NP) // 64 l-rows per pass-1 thread

// Branchless sorted-insert into (m1<=m2<=m3) three-smallest and (M1>=M2>=M3) three-largest.
__device__ __forceinline__ void upd6(float v,
                                     float& m1, float& m2, float& m3,
                                     float& M1, float& M2, float& M3) {
    float nm3 = fminf(m3, fmaxf(m2, v));
    float nm2 = __builtin_amdgcn_fmed3f(m1, m2, v);
    m1 = fminf(m1, v);
    m2 = nm2;
    m3 = nm3;
    float nM3 = fmaxf(M3, fminf(M2, v));
    float nM2 = __builtin_amdgcn_fmed3f(M1, M2, v);
    M1 = fmaxf(M1, v);
    M2 = nM2;
    M3 = nM3;
}

// Pass 1: grid = NB*S1 blocks, 256 threads. Thread t: channels c4=(t&63)*4, sub=t>>6.
// Each thread scans CHUNK consecutive l-rows with float4 loads (wave covers full 1KB C-row).
// Partials -> ws[b][p][k][c], coalesced float4 stores.
__global__ __launch_bounds__(256) void pass1_partials(const float* __restrict__ x,
                                                      float* __restrict__ ws) {
    const int b   = blockIdx.x / S1;
    const int s   = blockIdx.x - b * S1;
    const int t   = threadIdx.x;
    const int c4  = (t & 63) << 2;
    const int sub = t >> 6;
    const int p   = (s << 2) + sub;
    const int l0  = p * CHUNK;

    const float* base = x + ((size_t)b * NL + l0) * NC + c4;

    float m1[4], m2[4], m3[4], M1[4], M2[4], M3[4];
#pragma unroll
    for (int j = 0; j < 4; ++j) {
        m1[j] = m2[j] = m3[j] = INFINITY;
        M1[j] = M2[j] = M3[j] = -INFINITY;
    }

#pragma unroll 8
    for (int i = 0; i < CHUNK; ++i) {
        float4 v = *(const float4*)(base + (size_t)i * NC);
        upd6(v.x, m1[0], m2[0], m3[0], M1[0], M2[0], M3[0]);
        upd6(v.y, m1[1], m2[1], m3[1], M1[1], M2[1], M3[1]);
        upd6(v.z, m1[2], m2[2], m3[2], M1[2], M2[2], M3[2]);
        upd6(v.w, m1[3], m2[3], m3[3], M1[3], M2[3], M3[3]);
    }

    float* w = ws + ((size_t)(b * NP + p) * 6) * NC + c4;
    *(float4*)(w + 0 * NC) = make_float4(m1[0], m1[1], m1[2], m1[3]);
    *(float4*)(w + 1 * NC) = make_float4(m2[0], m2[1], m2[2], m2[3]);
    *(float4*)(w + 2 * NC) = make_float4(m3[0], m3[1], m3[2], m3[3]);
    *(float4*)(w + 3 * NC) = make_float4(M1[0], M1[1], M1[2], M1[3]);
    *(float4*)(w + 4 * NC) = make_float4(M2[0], M2[1], M2[2], M2[3]);
    *(float4*)(w + 5 * NC) = make_float4(M3[0], M3[1], M3[2], M3[3]);
}

// Pass 2: grid = NB*4 blocks, 256 threads. Block handles (b, 64 channels).
// lane cl = channel-in-group, sub = which quarter of the NP partials.
// Each thread merges NP/4 partials (coalesced across cl), then 4 sub-trackers
// merge through LDS (tracker values are genuine data elements, so re-feeding
// them through upd6 is exact).
__global__ __launch_bounds__(256) void pass2_merge(const float* __restrict__ ws,
                                                   float* __restrict__ out) {
    const int t   = threadIdx.x;
    const int cl  = t & 63;
    const int sub = t >> 6;               // 0..3
    const int b   = blockIdx.x >> 2;
    const int cg  = blockIdx.x & 3;
    const int c   = (cg << 6) + cl;

    float m1 = INFINITY, m2 = INFINITY, m3 = INFINITY;
    float M1 = -INFINITY, M2 = -INFINITY, M3 = -INFINITY;

    const float* w = ws + ((size_t)b * NP * 6) * NC + c;
    const int p0 = sub * (NP / 4);
#pragma unroll 4
    for (int p = 0; p < NP / 4; ++p) {
        const float* wp = w + (size_t)(p0 + p) * 6 * NC;
#pragma unroll
        for (int k = 0; k < 6; ++k)
            upd6(wp[(size_t)k * NC], m1, m2, m3, M1, M2, M3);
    }

    __shared__ float lds[4][64][6];
    lds[sub][cl][0] = m1; lds[sub][cl][1] = m2; lds[sub][cl][2] = m3;
    lds[sub][cl][3] = M1; lds[sub][cl][4] = M2; lds[sub][cl][5] = M3;
    __syncthreads();

    if (sub == 0) {
#pragma unroll
        for (int s2 = 1; s2 < 4; ++s2)
#pragma unroll
            for (int k = 0; k < 6; ++k)
                upd6(lds[s2][cl][k], m1, m2, m3, M1, M2, M3);
        float* o = out + ((size_t)b * NC + c) * 6;
        o[0] = m1; o[1] = m2; o[2] = m3;
        o[3] = M1; o[4] = M2; o[5] = M3;
    }
}

// Fallback if workspace is too small: one thread per (b, 4 channels), full-column scan.
__global__ __launch_bounds__(64) void direct_scan(const float* __restrict__ x,
                                                  float* __restrict__ out) {
    const int b  = blockIdx.x;
    const int c4 = threadIdx.x << 2;

    float m1[4], m2[4], m3[4], M1[4], M2[4], M3[4];
#pragma unroll
    for (int j = 0; j < 4; ++j) {
        m1[j] = m2[j] = m3[j] = INFINITY;
        M1[j] = M2[j] = M3[j] = -INFINITY;
    }

    const float* base = x + (size_t)b * NL * NC + c4;
#pragma unroll 4
    for (int i = 0; i < NL; ++i) {
        float4 v = *(const float4*)(base + (size_t)i * NC);
        upd6(v.x, m1[0], m2[0], m3[0], M1[0], M2[0], M3[0]);
        upd6(v.y, m1[1], m2[1], m3[1], M1[1], M2[1], M3[1]);
        upd6(v.z, m1[2], m2[2], m3[2], M1[2], M2[2], M3[2]);
        upd6(v.w, m1[3], m2[3], m3[3], M1[3], M2[3], M3[3]);
    }

#pragma unroll
    for (int j = 0; j < 4; ++j) {
        float* o = out + ((size_t)b * NC + c4 + j) * 6;
        o[0] = m1[j]; o[1] = m2[j]; o[2] = m3[j];
        o[3] = M1[j]; o[4] = M2[j]; o[5] = M3[j];
    }
}

extern "C" void kernel_launch(void* const* d_in, const int* in_sizes, int n_in,
                              void* d_out, int out_size, void* d_ws, size_t ws_size,
                              hipStream_t stream) {
    const float* x = (const float*)d_in[0];
    float* out = (float*)d_out;

    const size_t ws_need = (size_t)NB * NP * 6 * NC * 4;  // ~25.2 MB
    if (ws_need <= ws_size) {
        float* ws = (float*)d_ws;
        pass1_partials<<<NB * S1, 256, 0, stream>>>(x, ws);
        pass2_merge<<<NB * 4, 256, 0, stream>>>(ws, out);
    } else {
        direct_scan<<<NB, 64, 0, stream>>>(x, out);
    }
}

// Round 4
// 336.760 us; speedup vs baseline: 1.1353x; 1.0903x over previous
//
#include <hip/hip_runtime.h>
#include <math.h>

// Problem: x[B=32][L=8192][C=256] f32 -> per (b,c): 3 smallest (asc) + 3 largest (desc) over L.
#define NB 32
#define NL 8192
#define NC 256
#define S1 32            // pass-1 blocks per batch; also NP (one merged partial set per block)
#define NP S1
#define CHUNK (NL / (S1 * 4))  // 64 l-rows per pass-1 thread (4 sub-scans per block)

typedef float vfloat4 __attribute__((ext_vector_type(4)));  // native vec for nontemporal builtin

// Branchless sorted-insert into (m1<=m2<=m3) three-smallest and (M1>=M2>=M3) three-largest.
__device__ __forceinline__ void upd6(float v,
                                     float& m1, float& m2, float& m3,
                                     float& M1, float& M2, float& M3) {
    float nm3 = fminf(m3, fmaxf(m2, v));
    float nm2 = __builtin_amdgcn_fmed3f(m1, m2, v);
    m1 = fminf(m1, v);
    m2 = nm2;
    m3 = nm3;
    float nM3 = fmaxf(M3, fminf(M2, v));
    float nM2 = __builtin_amdgcn_fmed3f(M1, M2, v);
    M1 = fmaxf(M1, v);
    M2 = nM2;
    M3 = nM3;
}

// Pass 1: grid = NB*S1 blocks, 256 threads. Thread t: channels c4=(t&63)*4, sub=t>>6.
// Each thread streams CHUNK l-rows (float4, nontemporal). The block's 4 sub-trackers are
// merged through LDS, leaving ONE partial set per block -> ws[b][s][k][c] (6.3 MB total).
__global__ __launch_bounds__(256) void pass1_partials(const float* __restrict__ x,
                                                      float* __restrict__ ws) {
    const int b   = blockIdx.x / S1;
    const int s   = blockIdx.x - b * S1;
    const int t   = threadIdx.x;
    const int c4  = (t & 63) << 2;
    const int sub = t >> 6;
    const int l0  = ((s << 2) + sub) * CHUNK;

    const float* base = x + ((size_t)b * NL + l0) * NC + c4;

    float m1[4], m2[4], m3[4], M1[4], M2[4], M3[4];
#pragma unroll
    for (int j = 0; j < 4; ++j) {
        m1[j] = m2[j] = m3[j] = INFINITY;
        M1[j] = M2[j] = M3[j] = -INFINITY;
    }

#pragma unroll 8
    for (int i = 0; i < CHUNK; ++i) {
        vfloat4 v = __builtin_nontemporal_load((const vfloat4*)(base + (size_t)i * NC));
        upd6(v.x, m1[0], m2[0], m3[0], M1[0], M2[0], M3[0]);
        upd6(v.y, m1[1], m2[1], m3[1], M1[1], M2[1], M3[1]);
        upd6(v.z, m1[2], m2[2], m3[2], M1[2], M2[2], M3[2]);
        upd6(v.w, m1[3], m2[3], m3[3], M1[3], M2[3], M3[3]);
    }

    // In-block merge of the 4 sub-trackers: lds[sub][c][k]
    __shared__ float lds[4][NC][6];
#pragma unroll
    for (int j = 0; j < 4; ++j) {
        lds[sub][c4 + j][0] = m1[j]; lds[sub][c4 + j][1] = m2[j]; lds[sub][c4 + j][2] = m3[j];
        lds[sub][c4 + j][3] = M1[j]; lds[sub][c4 + j][4] = M2[j]; lds[sub][c4 + j][5] = M3[j];
    }
    __syncthreads();

    // Thread t now owns channel c = t. Merge 4 subs; write ws[b][s][k][c] (1KB/k coalesced).
    const int c = t;
    float a1 = INFINITY, a2 = INFINITY, a3 = INFINITY;
    float A1 = -INFINITY, A2 = -INFINITY, A3 = -INFINITY;
#pragma unroll
    for (int s2 = 0; s2 < 4; ++s2)
#pragma unroll
        for (int k = 0; k < 6; ++k)
            upd6(lds[s2][c][k], a1, a2, a3, A1, A2, A3);

    float* w = ws + (((size_t)(b * NP + s) * 6) * NC) + c;
    w[0 * NC] = a1; w[1 * NC] = a2; w[2 * NC] = a3;
    w[3 * NC] = A1; w[4 * NC] = A2; w[5 * NC] = A3;
}

// Pass 2: grid = NB*4 blocks, 256 threads. Block = (b, 64 channels); cl = channel lane,
// sub = quarter of the NP partial sets. 48 coalesced loads/thread, LDS 4->1 merge.
__global__ __launch_bounds__(256) void pass2_merge(const float* __restrict__ ws,
                                                   float* __restrict__ out) {
    const int t   = threadIdx.x;
    const int cl  = t & 63;
    const int sub = t >> 6;               // 0..3
    const int b   = blockIdx.x >> 2;
    const int cg  = blockIdx.x & 3;
    const int c   = (cg << 6) + cl;

    float m1 = INFINITY, m2 = INFINITY, m3 = INFINITY;
    float M1 = -INFINITY, M2 = -INFINITY, M3 = -INFINITY;

    const float* w = ws + ((size_t)b * NP * 6) * NC + c;
    const int p0 = sub * (NP / 4);
#pragma unroll
    for (int p = 0; p < NP / 4; ++p) {
        const float* wp = w + (size_t)(p0 + p) * 6 * NC;
#pragma unroll
        for (int k = 0; k < 6; ++k)
            upd6(wp[(size_t)k * NC], m1, m2, m3, M1, M2, M3);
    }

    __shared__ float lds[4][64][6];
    lds[sub][cl][0] = m1; lds[sub][cl][1] = m2; lds[sub][cl][2] = m3;
    lds[sub][cl][3] = M1; lds[sub][cl][4] = M2; lds[sub][cl][5] = M3;
    __syncthreads();

    if (sub == 0) {
#pragma unroll
        for (int s2 = 1; s2 < 4; ++s2)
#pragma unroll
            for (int k = 0; k < 6; ++k)
                upd6(lds[s2][cl][k], m1, m2, m3, M1, M2, M3);
        float* o = out + ((size_t)b * NC + c) * 6;
        o[0] = m1; o[1] = m2; o[2] = m3;
        o[3] = M1; o[4] = M2; o[5] = M3;
    }
}

// Fallback if workspace is too small: one thread per (b, 4 channels), full-column scan.
__global__ __launch_bounds__(64) void direct_scan(const float* __restrict__ x,
                                                  float* __restrict__ out) {
    const int b  = blockIdx.x;
    const int c4 = threadIdx.x << 2;

    float m1[4], m2[4], m3[4], M1[4], M2[4], M3[4];
#pragma unroll
    for (int j = 0; j < 4; ++j) {
        m1[j] = m2[j] = m3[j] = INFINITY;
        M1[j] = M2[j] = M3[j] = -INFINITY;
    }

    const float* base = x + (size_t)b * NL * NC + c4;
#pragma unroll 4
    for (int i = 0; i < NL; ++i) {
        float4 v = *(const float4*)(base + (size_t)i * NC);
        upd6(v.x, m1[0], m2[0], m3[0], M1[0], M2[0], M3[0]);
        upd6(v.y, m1[1], m2[1], m3[1], M1[1], M2[1], M3[1]);
        upd6(v.z, m1[2], m2[2], m3[2], M1[2], M2[2], M3[2]);
        upd6(v.w, m1[3], m2[3], m3[3], M1[3], M2[3], M3[3]);
    }

#pragma unroll
    for (int j = 0; j < 4; ++j) {
        float* o = out + ((size_t)b * NC + c4 + j) * 6;
        o[0] = m1[j]; o[1] = m2[j]; o[2] = m3[j];
        o[3] = M1[j]; o[4] = M2[j]; o[5] = M3[j];
    }
}

extern "C" void kernel_launch(void* const* d_in, const int* in_sizes, int n_in,
                              void* d_out, int out_size, void* d_ws, size_t ws_size,
                              hipStream_t stream) {
    const float* x = (const float*)d_in[0];
    float* out = (float*)d_out;

    const size_t ws_need = (size_t)NB * NP * 6 * NC * 4;  // ~6.3 MB
    if (ws_need <= ws_size) {
        float* ws = (float*)d_ws;
        pass1_partials<<<NB * S1, 256, 0, stream>>>(x, ws);
        pass2_merge<<<NB * 4, 256, 0, stream>>>(ws, out);
    } else {
        direct_scan<<<NB, 64, 0, stream>>>(x, out);
    }
}